// Round 4
// baseline (622.398 us; speedup 1.0000x reference)
//
#include <hip/hip_runtime.h>
#include <math.h>

#define TLEN   8192
#define BROWS  4096
#define NT     256
#define TILE   2048
#define CHUNK  8          /* TILE / NT */
#define NTILES (TLEN / TILE)
#define GAMMA  0.99f
#define EPSN   1e-9
#define GRID   1024       /* 4 blocks/CU via __launch_bounds__(256,4): capacity = 1024 */
#define RPB    (BROWS / GRID)   /* 4 rows per block, sequential */

typedef float f4 __attribute__((ext_vector_type(4)));

// ---------------------------------------------------------------------------
// Fully fused kernel, NO cooperative API (round-3 coop launch failed silently:
// absmax == max|ref| -> out was never written).
//
// Phase 1: round-1 harness-verified scan structure (register prefetch of next
//          tile, per-k LDS composite slots, ONE barrier/tile), looped over the
//          block's 4 rows. Per-row invstd -> LDS; block's summed rowSums ->
//          one f64 atomicAdd into a global accumulator.
// Barrier: software grid barrier from device-scope atomics only (G12/G16):
//          tid0: atomicAdd(tsum) ; threadfence ; atomicAdd(counter) ; spin on
//          atomic-acquire load of counter (with sleep + bail-out cap).
//          All cross-block data flows through atomics -> no XCD-coherence
//          hazard for plain loads.
// Phase 3: each block normalizes its OWN 4 rows (same-CU data, L2/L3-hot).
// ---------------------------------------------------------------------------
__global__ __launch_bounds__(NT, 4) void er_fused(const float* __restrict__ rew,
                                                  const float* __restrict__ don,
                                                  float* __restrict__ out,
                                                  double* __restrict__ tsum,
                                                  unsigned* __restrict__ counter) {
  __shared__ float  wgA[NTILES][4], wgP[NTILES][4];
  __shared__ double red[8];
  __shared__ float  invLds[RPB];
  __shared__ float  meanLds;

  const int tid  = threadIdx.x;
  const int lane = tid & 63;
  const int wv   = tid >> 6;
  const int row0 = blockIdx.x * RPB;

  double bsum = 0.0;   // meaningful on tid0 only

  for (int rr = 0; rr < RPB; ++rr) {
    const size_t rbase = (size_t)(row0 + rr) * TLEN;
    const f4* gr = (const f4*)(rew + rbase);
    const f4* gd = (const f4*)(don + rbase);

    // preload last tile
    f4 r0, r1, d0, d1;
    {
      const int f = (NTILES - 1) * (TILE / 4) + 2 * tid;
      r0 = gr[f]; r1 = gr[f + 1];
      d0 = gd[f]; d1 = gd[f + 1];
    }

    double accS = 0.0, accQ = 0.0;
    float  tc = 0.f;   // carry entering the current tile from the right

    for (int k = NTILES - 1; k >= 0; --k) {
      const bool more = (k > 0);
      f4 pr0, pr1, pd0, pd1;
      if (more) {
        const int f = (k - 1) * (TILE / 4) + 2 * tid;
        pr0 = gr[f]; pr1 = gr[f + 1];
        pd0 = gd[f]; pd1 = gd[f + 1];
      }

      // --- unpack own 8-element chunk; cv = gamma*(1-done) ---
      float rv[CHUNK], cv[CHUNK];
      rv[0] = r0.x; rv[1] = r0.y; rv[2] = r0.z; rv[3] = r0.w;
      rv[4] = r1.x; rv[5] = r1.y; rv[6] = r1.z; rv[7] = r1.w;
      cv[0] = fmaf(-GAMMA, d0.x, GAMMA);
      cv[1] = fmaf(-GAMMA, d0.y, GAMMA);
      cv[2] = fmaf(-GAMMA, d0.z, GAMMA);
      cv[3] = fmaf(-GAMMA, d0.w, GAMMA);
      cv[4] = fmaf(-GAMMA, d1.x, GAMMA);
      cv[5] = fmaf(-GAMMA, d1.y, GAMMA);
      cv[6] = fmaf(-GAMMA, d1.z, GAMMA);
      cv[7] = fmaf(-GAMMA, d1.w, GAMMA);

      // --- local suffix scan of affine maps T_j(x) = rv + cv*x ---
      float A = 0.f, P = 1.f;
#pragma unroll
      for (int j = CHUNK - 1; j >= 0; --j) {
        A = fmaf(cv[j], A, rv[j]);
        P *= cv[j];
        rv[j] = A;
        cv[j] = P;
      }

      // --- wave inclusive suffix scan of (A,P) composites ---
      float sA = A, sP = P;
#pragma unroll
      for (int d = 1; d < 64; d <<= 1) {
        const float tA = __shfl_down(sA, d);
        const float tP = __shfl_down(sP, d);
        if (lane + d < 64) { sA = fmaf(sP, tA, sA); sP *= tP; }
      }
      if (lane == 0) { wgA[k][wv] = sA; wgP[k][wv] = sP; }
      __syncthreads();   // only barrier this tile (per-k slots -> no WAR)

      // carry entering this wave = waves (wv,3] composed, applied to tc
      float wc = tc;
#pragma unroll
      for (int j = 3; j >= 1; --j) {
        const float nw = fmaf(wgP[k][j], wc, wgA[k][j]);
        wc = (j > wv) ? nw : wc;
      }
      // next tile's carry = all 4 waves composed, applied to tc
      float tcn = tc;
#pragma unroll
      for (int j = 3; j >= 0; --j) tcn = fmaf(wgP[k][j], tcn, wgA[k][j]);

      // exclusive within wave (lanes above), then apply wave carry
      float eA = __shfl_down(sA, 1);
      float eP = __shfl_down(sP, 1);
      if (lane == 63) { eA = 0.f; eP = 1.f; }
      const float carry = fmaf(eP, wc, eA);

      // --- fixup, store, stats ---
      float fsum = 0.f, fsq = 0.f;
      float o[CHUNK];
#pragma unroll
      for (int j = 0; j < CHUNK; ++j) {
        const float r = fmaf(cv[j], carry, rv[j]);
        o[j] = r;
        fsum += r;
        fsq  = fmaf(r, r, fsq);
      }
      f4* go = (f4*)(out + rbase + (size_t)k * TILE) + 2 * tid;
      f4 o0; o0.x = o[0]; o0.y = o[1]; o0.z = o[2]; o0.w = o[3];
      f4 o1; o1.x = o[4]; o1.y = o[5]; o1.z = o[6]; o1.w = o[7];
      go[0] = o0;
      go[1] = o1;
      accS += (double)fsum;
      accQ += (double)fsq;
      tc = tcn;

      if (more) { r0 = pr0; r1 = pr1; d0 = pd0; d1 = pd1; }
    }

    // --- block reduction (double) for this row's stats ---
    double ds = accS, dq = accQ;
#pragma unroll
    for (int d = 32; d >= 1; d >>= 1) {
      ds += __shfl_down(ds, d);
      dq += __shfl_down(dq, d);
    }
    if (lane == 0) { red[wv] = ds; red[4 + wv] = dq; }
    __syncthreads();
    if (tid == 0) {
      const double s = red[0] + red[1] + red[2] + red[3];
      const double q = red[4] + red[5] + red[6] + red[7];
      bsum += s;
      double var = (q - s * s / (double)TLEN) / (double)(TLEN - 1);
      if (var < 0.0) var = 0.0;
      invLds[rr] = (float)(1.0 / (sqrt(var) + EPSN));
    }
    // NOTE: no barrier needed here: next row's first touch of shared state
    // (wgA[k] write -> __syncthreads) orders everything; tid0's red[] reads
    // complete before it participates in that barrier.
  }

  // ---- software grid barrier: device-scope atomics only ----
  if (tid == 0) {
    atomicAdd(tsum, bsum);                       // device-scope f64 atomic
    __threadfence();                             // order tsum-add before counter-add
    atomicAdd(counter, 1u);
    unsigned it = 0;
    while (__hip_atomic_load(counter, __ATOMIC_ACQUIRE, __HIP_MEMORY_SCOPE_AGENT) < GRID) {
      __builtin_amdgcn_s_sleep(32);
      if (++it > (1u << 22)) break;              // bail-out: degrade, never hang
    }
    const unsigned long long rawv =
        __hip_atomic_load((unsigned long long*)tsum, __ATOMIC_RELAXED,
                          __HIP_MEMORY_SCOPE_AGENT);
    const double t = __builtin_bit_cast(double, rawv);
    meanLds = (float)(t / ((double)BROWS * (double)TLEN));
  }
  __syncthreads();
  const float mean = meanLds;

  // ---- Phase 3: normalize own rows (block wrote them; L2/L3-resident) ----
  for (int rr = 0; rr < RPB; ++rr) {
    const float inv = invLds[rr];
    f4* o4 = (f4*)(out + (size_t)(row0 + rr) * TLEN);
#pragma unroll
    for (int i = tid; i < TLEN / 4; i += NT) {
      f4 v = o4[i];
      v.x = (v.x - mean) * inv;
      v.y = (v.y - mean) * inv;
      v.z = (v.z - mean) * inv;
      v.w = (v.w - mean) * inv;
      o4[i] = v;
    }
  }
}

extern "C" void kernel_launch(void* const* d_in, const int* in_sizes, int n_in,
                              void* d_out, int out_size, void* d_ws, size_t ws_size,
                              hipStream_t stream) {
  const float* rew = (const float*)d_in[0];
  const float* don = (const float*)d_in[1];
  float* out = (float*)d_out;

  double*   tsum    = (double*)d_ws;
  unsigned* counter = (unsigned*)((char*)d_ws + 8);

  // reset barrier state every launch/replay (capture-safe; harness uses the
  // same API in its own reset path)
  hipMemsetAsync(d_ws, 0, 16, stream);
  er_fused<<<GRID, NT, 0, stream>>>(rew, don, out, tsum, counter);
}

// Round 5
// 354.741 us; speedup vs baseline: 1.7545x; 1.7545x over previous
//
#include <hip/hip_runtime.h>
#include <math.h>

#define TLEN   8192
#define BROWS  4096
#define NT     256
#define WPB    (NT / 64)        /* 4 waves per block, one row each */
#define GRID   (BROWS / WPB)    /* 1024 blocks */
#define TPW    512              /* elems per wave-tile */
#define NTW    (TLEN / TPW)     /* 16 tiles per row */
#define GAMMA  0.99f
#define EPSN   1e-9

typedef float f4 __attribute__((ext_vector_type(4)));

// ---------------------------------------------------------------------------
// One-wave tile scan: lane l owns elems [8l, 8l+8) of a 512-elem tile.
// Affine suffix-scan identical to the verified round-1 math, specialized to a
// single wave (wave carry == tc, tile composite broadcast from lane 0).
// ---------------------------------------------------------------------------
__device__ __forceinline__ void scan_tile(const f4 r0, const f4 r1,
                                          const f4 d0, const f4 d1,
                                          const int lane, float& tc,
                                          float* __restrict__ dst,
                                          double& accS, double& accQ) {
  float rv[8], cv[8];
  rv[0] = r0.x; rv[1] = r0.y; rv[2] = r0.z; rv[3] = r0.w;
  rv[4] = r1.x; rv[5] = r1.y; rv[6] = r1.z; rv[7] = r1.w;
  cv[0] = fmaf(-GAMMA, d0.x, GAMMA);
  cv[1] = fmaf(-GAMMA, d0.y, GAMMA);
  cv[2] = fmaf(-GAMMA, d0.z, GAMMA);
  cv[3] = fmaf(-GAMMA, d0.w, GAMMA);
  cv[4] = fmaf(-GAMMA, d1.x, GAMMA);
  cv[5] = fmaf(-GAMMA, d1.y, GAMMA);
  cv[6] = fmaf(-GAMMA, d1.z, GAMMA);
  cv[7] = fmaf(-GAMMA, d1.w, GAMMA);

  // local suffix scan of affine maps T_j(x) = rv + cv*x
  float A = 0.f, P = 1.f;
#pragma unroll
  for (int j = 7; j >= 0; --j) {
    A = fmaf(cv[j], A, rv[j]);
    P *= cv[j];
    rv[j] = A;
    cv[j] = P;
  }

  // wave inclusive suffix scan of (A,P)
  float sA = A, sP = P;
#pragma unroll
  for (int d = 1; d < 64; d <<= 1) {
    const float tA = __shfl_down(sA, d);
    const float tP = __shfl_down(sP, d);
    if (lane + d < 64) { sA = fmaf(sP, tA, sA); sP *= tP; }
  }

  // exclusive (lanes above), then apply incoming carry tc
  float eA = __shfl_down(sA, 1);
  float eP = __shfl_down(sP, 1);
  if (lane == 63) { eA = 0.f; eP = 1.f; }
  const float carry = fmaf(eP, tc, eA);

  // whole-tile composite (lane 0 inclusive) -> carry for next tile (leftward)
  const float gA = __shfl(sA, 0);
  const float gP = __shfl(sP, 0);
  tc = fmaf(gP, tc, gA);

  // fixup, store, stats
  float fs = 0.f, fq = 0.f;
  float o[8];
#pragma unroll
  for (int j = 0; j < 8; ++j) {
    const float r = fmaf(cv[j], carry, rv[j]);
    o[j] = r;
    fs += r;
    fq  = fmaf(r, r, fq);
  }
  f4* go = (f4*)dst + 2 * lane;
  f4 o0; o0.x = o[0]; o0.y = o[1]; o0.z = o[2]; o0.w = o[3];
  f4 o1; o1.x = o[4]; o1.y = o[5]; o1.z = o[6]; o1.w = o[7];
  go[0] = o0;
  go[1] = o1;
  accS += (double)fs;
  accQ += (double)fq;
}

// ---------------------------------------------------------------------------
// K1: one ROW PER WAVE, zero __syncthreads in the data path (no forced
// vmcnt(0) drains, no wave convoying). Double-buffered register prefetch with
// named A/B buffers (rule #20: no runtime-indexed vector arrays) pinned by
// sched_barrier(0) after each issue block (rule #18) so the compiler cannot
// sink the loads to their use point (round-1's VGPR=40 proved it did exactly
// that). __launch_bounds__(256,4) gives the allocator a 128-VGPR budget so
// both buffers stay live.
// ---------------------------------------------------------------------------
__global__ __launch_bounds__(NT, 4) void er_scan(const float* __restrict__ rew,
                                                 const float* __restrict__ don,
                                                 float* __restrict__ out,
                                                 double* __restrict__ rowSum,
                                                 float* __restrict__ rowInv) {
  const int tid  = threadIdx.x;
  const int lane = tid & 63;
  const int wv   = tid >> 6;
  const int row  = blockIdx.x * WPB + wv;
  const size_t rbase = (size_t)row * TLEN;

  const f4* gr = (const f4*)(rew + rbase);
  const f4* gd = (const f4*)(don + rbase);
  float* ob = out + rbase;

  f4 aR0, aR1, aD0, aD1, bR0, bR1, bD0, bD1;
  {
    const int f = (NTW - 1) * (TPW / 4) + 2 * lane;
    aR0 = gr[f]; aR1 = gr[f + 1];
    aD0 = gd[f]; aD1 = gd[f + 1];
  }

  float tc = 0.f;
  double accS = 0.0, accQ = 0.0;

#pragma unroll
  for (int kk = 0; kk < NTW / 2; ++kk) {
    const int k = NTW - 1 - 2 * kk;     // 15,13,...,1 (compile-time)
    if (k >= 1) {
      const int f = (k - 1) * (TPW / 4) + 2 * lane;
      bR0 = gr[f]; bR1 = gr[f + 1];
      bD0 = gd[f]; bD1 = gd[f + 1];
    }
    __builtin_amdgcn_sched_barrier(0);   // pin issue: loads may not sink
    scan_tile(aR0, aR1, aD0, aD1, lane, tc, ob + (size_t)k * TPW, accS, accQ);

    if (k >= 2) {
      const int f = (k - 2) * (TPW / 4) + 2 * lane;
      aR0 = gr[f]; aR1 = gr[f + 1];
      aD0 = gd[f]; aD1 = gd[f + 1];
    }
    __builtin_amdgcn_sched_barrier(0);
    scan_tile(bR0, bR1, bD0, bD1, lane, tc, ob + (size_t)(k - 1) * TPW, accS, accQ);
  }

  // --- per-wave (per-row) stats reduction; no cross-wave communication ---
  double ds = accS, dq = accQ;
#pragma unroll
  for (int d = 32; d >= 1; d >>= 1) {
    ds += __shfl_down(ds, d);
    dq += __shfl_down(dq, d);
  }
  if (lane == 0) {
    rowSum[row] = ds;
    double var = (dq - ds * ds / (double)TLEN) / (double)(TLEN - 1);
    if (var < 0.0) var = 0.0;
    rowInv[row] = (float)(1.0 / (sqrt(var) + EPSN));
  }
}

// ---------------------------------------------------------------------------
// K2: reduce 4096 per-row sums -> global mean (single block)
// ---------------------------------------------------------------------------
__global__ __launch_bounds__(256) void er_mean(const double* __restrict__ rowSum,
                                               float* __restrict__ meanPtr) {
  const int tid = threadIdx.x;
  double s = 0.0;
  for (int i = tid; i < BROWS; i += 256) s += rowSum[i];
#pragma unroll
  for (int d = 32; d >= 1; d >>= 1) s += __shfl_down(s, d);
  __shared__ double red[4];
  const int lane = tid & 63, wv = tid >> 6;
  if (lane == 0) red[wv] = s;
  __syncthreads();
  if (tid == 0) {
    const double t = red[0] + red[1] + red[2] + red[3];
    *meanPtr = (float)(t / ((double)BROWS * (double)TLEN));
  }
}

// ---------------------------------------------------------------------------
// K3: out = (out - mean) * invstd[row]; round-0 per-row form (measured ~10us
// better than the grid-stride variant across rounds 0 vs 1/2).
// ---------------------------------------------------------------------------
__global__ __launch_bounds__(256) void er_norm(float* __restrict__ out,
                                               const float* __restrict__ rowInv,
                                               const float* __restrict__ meanPtr) {
  const int row = blockIdx.x;
  const float mean = *meanPtr;
  const float inv  = rowInv[row];
  f4* o4 = (f4*)(out + (size_t)row * TLEN);
#pragma unroll
  for (int i = threadIdx.x; i < TLEN / 4; i += 256) {
    f4 v = o4[i];
    v.x = (v.x - mean) * inv;
    v.y = (v.y - mean) * inv;
    v.z = (v.z - mean) * inv;
    v.w = (v.w - mean) * inv;
    o4[i] = v;
  }
}

extern "C" void kernel_launch(void* const* d_in, const int* in_sizes, int n_in,
                              void* d_out, int out_size, void* d_ws, size_t ws_size,
                              hipStream_t stream) {
  const float* rew = (const float*)d_in[0];
  const float* don = (const float*)d_in[1];
  float* out = (float*)d_out;

  double* rowSum  = (double*)d_ws;
  float*  rowInv  = (float*)((char*)d_ws + BROWS * 8);
  float*  meanPtr = (float*)((char*)d_ws + BROWS * 8 + BROWS * 4);

  er_scan<<<GRID, NT, 0, stream>>>(rew, don, out, rowSum, rowInv);
  er_mean<<<1, 256, 0, stream>>>(rowSum, meanPtr);
  er_norm<<<BROWS, 256, 0, stream>>>(out, rowInv, meanPtr);
}

// Round 6
// 352.112 us; speedup vs baseline: 1.7676x; 1.0075x over previous
//
#include <hip/hip_runtime.h>
#include <math.h>

#define TLEN   8192
#define BROWS  4096
#define NT     256
#define WPB    (NT / 64)        /* 4 waves per block, one row each */
#define GRID   (BROWS / WPB)    /* 1024 blocks */
#define TPW    256              /* elems per wave-tile: ONE f4 per lane */
#define NTW    (TLEN / TPW)     /* 32 tiles per row */
#define GAMMA  0.99f
#define EPSN   1e-9

typedef float f4 __attribute__((ext_vector_type(4)));

// ---------------------------------------------------------------------------
// 256-elem tile scan: lane l owns elems [4l, 4l+4). Every global access in
// this kernel is a DENSE 1KB-per-instruction pattern (lane i at base+16B*i),
// i.e. exactly er_norm's instruction shape -- er_norm measures 4.6 TB/s on
// this same data while all 32B-lane-stride scan variants pinned at 2.4.
// ---------------------------------------------------------------------------
__device__ __forceinline__ void scan_tile4(const f4 r, const f4 d,
                                           const int lane, float& tc,
                                           float* __restrict__ dst,
                                           double& accS, double& accQ) {
  float rv[4], cv[4];
  rv[0] = r.x; rv[1] = r.y; rv[2] = r.z; rv[3] = r.w;
  cv[0] = fmaf(-GAMMA, d.x, GAMMA);
  cv[1] = fmaf(-GAMMA, d.y, GAMMA);
  cv[2] = fmaf(-GAMMA, d.z, GAMMA);
  cv[3] = fmaf(-GAMMA, d.w, GAMMA);

  // local suffix scan of affine maps T_j(x) = rv + cv*x
  float A = 0.f, P = 1.f;
#pragma unroll
  for (int j = 3; j >= 0; --j) {
    A = fmaf(cv[j], A, rv[j]);
    P *= cv[j];
    rv[j] = A;
    cv[j] = P;
  }

  // wave inclusive suffix scan of (A,P)
  float sA = A, sP = P;
#pragma unroll
  for (int dd = 1; dd < 64; dd <<= 1) {
    const float tA = __shfl_down(sA, dd);
    const float tP = __shfl_down(sP, dd);
    if (lane + dd < 64) { sA = fmaf(sP, tA, sA); sP *= tP; }
  }

  // exclusive (lanes above), apply incoming carry tc
  float eA = __shfl_down(sA, 1);
  float eP = __shfl_down(sP, 1);
  if (lane == 63) { eA = 0.f; eP = 1.f; }
  const float carry = fmaf(eP, tc, eA);

  // whole-tile composite (lane 0 inclusive) -> carry for next tile leftward
  const float gA = __shfl(sA, 0);
  const float gP = __shfl(sP, 0);
  tc = fmaf(gP, tc, gA);

  // fixup, stats, dense f4 store
  float fs = 0.f, fq = 0.f;
  f4 o;
  {
    const float r0 = fmaf(cv[0], carry, rv[0]);
    const float r1 = fmaf(cv[1], carry, rv[1]);
    const float r2 = fmaf(cv[2], carry, rv[2]);
    const float r3 = fmaf(cv[3], carry, rv[3]);
    o.x = r0; o.y = r1; o.z = r2; o.w = r3;
    fs = (r0 + r1) + (r2 + r3);
    fq = fmaf(r0, r0, fmaf(r1, r1, fmaf(r2, r2, r3 * r3)));
  }
  ((f4*)dst)[lane] = o;
  accS += (double)fs;
  accQ += (double)fq;
}

// ---------------------------------------------------------------------------
// K1: one ROW PER WAVE, zero barriers, zero LDS. Distance-2 register prefetch
// via a 4-slot named-buffer rotation (period-4 unrolled: all slot indices are
// compile-time -- rule #20), sched_barrier(0) after each issue block pins the
// loads (rule #18). Steady state: 2 tiles (4 loads) outstanding per wave while
// the current tile's ~150cy dependent scan chain runs.
// ---------------------------------------------------------------------------
__global__ __launch_bounds__(NT, 4) void er_scan(const float* __restrict__ rew,
                                                 const float* __restrict__ don,
                                                 float* __restrict__ out,
                                                 double* __restrict__ rowSum,
                                                 float* __restrict__ rowInv) {
  const int tid  = threadIdx.x;
  const int lane = tid & 63;
  const int wv   = tid >> 6;
  const int row  = blockIdx.x * WPB + wv;
  const size_t rbase = (size_t)row * TLEN;

  const f4* gr = (const f4*)(rew + rbase);
  const f4* gd = (const f4*)(don + rbase);
  float* ob = out + rbase;

  // slot s holds tiles k with (k & 3) == s
  f4 bR0, bR1, bR2, bR3, bD0, bD1, bD2, bD3;

  // prologue: tiles 31 (slot 3) and 30 (slot 2)
  bR3 = gr[31 * 64 + lane]; bD3 = gd[31 * 64 + lane];
  bR2 = gr[30 * 64 + lane]; bD2 = gd[30 * 64 + lane];

  double accS = 0.0, accQ = 0.0;
  float  tc = 0.f;

#pragma unroll
  for (int kb = 31; kb >= 3; kb -= 4) {
    // pos0: issue kb-2 (slot 1), consume kb (slot 3)
    if (kb - 2 >= 0) { bR1 = gr[(kb - 2) * 64 + lane]; bD1 = gd[(kb - 2) * 64 + lane]; }
    __builtin_amdgcn_sched_barrier(0);
    scan_tile4(bR3, bD3, lane, tc, ob + (size_t)kb * TPW, accS, accQ);

    // pos1: issue kb-3 (slot 0), consume kb-1 (slot 2)
    if (kb - 3 >= 0) { bR0 = gr[(kb - 3) * 64 + lane]; bD0 = gd[(kb - 3) * 64 + lane]; }
    __builtin_amdgcn_sched_barrier(0);
    scan_tile4(bR2, bD2, lane, tc, ob + (size_t)(kb - 1) * TPW, accS, accQ);

    // pos2: issue kb-4 (slot 3), consume kb-2 (slot 1)
    if (kb - 4 >= 0) { bR3 = gr[(kb - 4) * 64 + lane]; bD3 = gd[(kb - 4) * 64 + lane]; }
    __builtin_amdgcn_sched_barrier(0);
    scan_tile4(bR1, bD1, lane, tc, ob + (size_t)(kb - 2) * TPW, accS, accQ);

    // pos3: issue kb-5 (slot 2), consume kb-3 (slot 0)
    if (kb - 5 >= 0) { bR2 = gr[(kb - 5) * 64 + lane]; bD2 = gd[(kb - 5) * 64 + lane]; }
    __builtin_amdgcn_sched_barrier(0);
    scan_tile4(bR0, bD0, lane, tc, ob + (size_t)(kb - 3) * TPW, accS, accQ);
  }

  // --- per-wave (per-row) stats reduction; no cross-wave communication ---
  double ds = accS, dq = accQ;
#pragma unroll
  for (int d = 32; d >= 1; d >>= 1) {
    ds += __shfl_down(ds, d);
    dq += __shfl_down(dq, d);
  }
  if (lane == 0) {
    rowSum[row] = ds;
    double var = (dq - ds * ds / (double)TLEN) / (double)(TLEN - 1);
    if (var < 0.0) var = 0.0;
    rowInv[row] = (float)(1.0 / (sqrt(var) + EPSN));
  }
}

// ---------------------------------------------------------------------------
// K2: reduce 4096 per-row sums -> global mean (single block)
// ---------------------------------------------------------------------------
__global__ __launch_bounds__(256) void er_mean(const double* __restrict__ rowSum,
                                               float* __restrict__ meanPtr) {
  const int tid = threadIdx.x;
  double s = 0.0;
  for (int i = tid; i < BROWS; i += 256) s += rowSum[i];
#pragma unroll
  for (int d = 32; d >= 1; d >>= 1) s += __shfl_down(s, d);
  __shared__ double red[4];
  const int lane = tid & 63, wv = tid >> 6;
  if (lane == 0) red[wv] = s;
  __syncthreads();
  if (tid == 0) {
    const double t = red[0] + red[1] + red[2] + red[3];
    *meanPtr = (float)(t / ((double)BROWS * (double)TLEN));
  }
}

// ---------------------------------------------------------------------------
// K3: out = (out - mean) * invstd[row]; per-row blocks (measures ~4.6 TB/s)
// ---------------------------------------------------------------------------
__global__ __launch_bounds__(256) void er_norm(float* __restrict__ out,
                                               const float* __restrict__ rowInv,
                                               const float* __restrict__ meanPtr) {
  const int row = blockIdx.x;
  const float mean = *meanPtr;
  const float inv  = rowInv[row];
  f4* o4 = (f4*)(out + (size_t)row * TLEN);
#pragma unroll
  for (int i = threadIdx.x; i < TLEN / 4; i += 256) {
    f4 v = o4[i];
    v.x = (v.x - mean) * inv;
    v.y = (v.y - mean) * inv;
    v.z = (v.z - mean) * inv;
    v.w = (v.w - mean) * inv;
    o4[i] = v;
  }
}

extern "C" void kernel_launch(void* const* d_in, const int* in_sizes, int n_in,
                              void* d_out, int out_size, void* d_ws, size_t ws_size,
                              hipStream_t stream) {
  const float* rew = (const float*)d_in[0];
  const float* don = (const float*)d_in[1];
  float* out = (float*)d_out;

  double* rowSum  = (double*)d_ws;
  float*  rowInv  = (float*)((char*)d_ws + BROWS * 8);
  float*  meanPtr = (float*)((char*)d_ws + BROWS * 8 + BROWS * 4);

  er_scan<<<GRID, NT, 0, stream>>>(rew, don, out, rowSum, rowInv);
  er_mean<<<1, 256, 0, stream>>>(rowSum, meanPtr);
  er_norm<<<BROWS, 256, 0, stream>>>(out, rowInv, meanPtr);
}